// Round 1
// baseline (2729.523 us; speedup 1.0000x reference)
//
#include <hip/hip_runtime.h>
#include <math.h>

#define TSTEPS 24
#define BB 64
#define DD 1536
#define RR 5120
#define NB 5
#define CC 100

// ---------- prep: Wp_m = Wp * proj_mask ; zero the 6 state buffers ----------
__global__ __launch_bounds__(256) void k_prep(const float* __restrict__ Wp,
                                              const float* __restrict__ pm,
                                              float* __restrict__ Wpm,
                                              float* __restrict__ zbuf) {
  size_t n = (size_t)RR * DD;
  size_t zn = 6ull * BB * RR;
  for (size_t i = (size_t)blockIdx.x * 256 + threadIdx.x; i < n;
       i += (size_t)gridDim.x * 256) {
    Wpm[i] = Wp[i] * pm[i];
    if (i < zn) zbuf[i] = 0.0f;
  }
}

// ---------- WlT[k][r] = Wl[r][k] * lat_mask[r][k] (masked transpose) ----------
__global__ __launch_bounds__(256) void k_transpose(const float* __restrict__ Wl,
                                                   const float* __restrict__ lm,
                                                   float* __restrict__ WlT) {
  __shared__ float tile[32][33];
  int k0 = blockIdx.x * 32;
  int r0 = blockIdx.y * 32;
  int tx = threadIdx.x;  // 0..31
  int ty = threadIdx.y;  // 0..7
  for (int i = ty; i < 32; i += 8) {
    size_t src = (size_t)(r0 + i) * RR + (k0 + tx);
    tile[i][tx] = Wl[src] * lm[src];
  }
  __syncthreads();
  for (int i = ty; i < 32; i += 8) {
    WlT[(size_t)(k0 + i) * RR + (r0 + tx)] = tile[tx][i];
  }
}

// ---------- LayerNorm over D=1536, one block per (t,b) row ----------
__global__ __launch_bounds__(256) void k_layernorm(const float* __restrict__ x,
                                                   const float* __restrict__ g,
                                                   const float* __restrict__ be,
                                                   float* __restrict__ xn) {
  __shared__ float red[4];
  int row = blockIdx.x;
  int tid = threadIdx.x;
  const float* xr = x + (size_t)row * DD;
  float v[6];
  float s = 0.f;
#pragma unroll
  for (int i = 0; i < 6; i++) { v[i] = xr[i * 256 + tid]; s += v[i]; }
  for (int o = 32; o > 0; o >>= 1) s += __shfl_down(s, o, 64);
  int wv = tid >> 6, lane = tid & 63;
  if (lane == 0) red[wv] = s;
  __syncthreads();
  float mu = (red[0] + red[1] + red[2] + red[3]) * (1.0f / DD);
  __syncthreads();
  float sq = 0.f;
#pragma unroll
  for (int i = 0; i < 6; i++) { float d = v[i] - mu; sq += d * d; }
  for (int o = 32; o > 0; o >>= 1) sq += __shfl_down(sq, o, 64);
  if (lane == 0) red[wv] = sq;
  __syncthreads();
  float var = (red[0] + red[1] + red[2] + red[3]) * (1.0f / DD);
  float sc = 1.0f / sqrtf(var + 1e-5f);
#pragma unroll
  for (int i = 0; i < 6; i++) {
    int c = i * 256 + tid;
    xn[(size_t)row * DD + c] = (v[i] - mu) * sc * g[c] + be[c];
  }
}

// ---------- drive = xn @ Wp_m^T + bp  (f32, 64x64 tile, 4x4 microtile) ----------
__global__ __launch_bounds__(256) void k_gemm_drive(const float* __restrict__ A,
                                                    const float* __restrict__ Bw,
                                                    const float* __restrict__ bp,
                                                    float* __restrict__ Co) {
  __shared__ __align__(16) float As[16][68];
  __shared__ __align__(16) float Bs[16][68];
  int tid = threadIdx.x;
  int m0 = blockIdx.y * 64;
  int n0 = blockIdx.x * 64;
  int lr = tid >> 2;  // 0..63 row in tile
  int lq = tid & 3;   // 0..3 k-quad
  int tx = tid & 15;
  int ty = tid >> 4;
  float acc[4][4] = {};
  const float4* Arow = (const float4*)(A + (size_t)(m0 + lr) * DD);
  const float4* Brow = (const float4*)(Bw + (size_t)(n0 + lr) * DD);
  for (int k0 = 0; k0 < DD; k0 += 16) {
    float4 av = Arow[(k0 >> 2) + lq];
    float4 bv = Brow[(k0 >> 2) + lq];
    __syncthreads();
    As[lq * 4 + 0][lr] = av.x; As[lq * 4 + 1][lr] = av.y;
    As[lq * 4 + 2][lr] = av.z; As[lq * 4 + 3][lr] = av.w;
    Bs[lq * 4 + 0][lr] = bv.x; Bs[lq * 4 + 1][lr] = bv.y;
    Bs[lq * 4 + 2][lr] = bv.z; Bs[lq * 4 + 3][lr] = bv.w;
    __syncthreads();
#pragma unroll
    for (int kk = 0; kk < 16; kk++) {
      float4 a4 = *(const float4*)&As[kk][ty * 4];
      float4 b4 = *(const float4*)&Bs[kk][tx * 4];
      float av2[4] = {a4.x, a4.y, a4.z, a4.w};
      float bv2[4] = {b4.x, b4.y, b4.z, b4.w};
#pragma unroll
      for (int i2 = 0; i2 < 4; i2++)
#pragma unroll
        for (int j2 = 0; j2 < 4; j2++) acc[i2][j2] += av2[i2] * bv2[j2];
    }
  }
  float bb[4];
#pragma unroll
  for (int j2 = 0; j2 < 4; j2++) bb[j2] = bp[n0 + tx * 4 + j2];
#pragma unroll
  for (int i2 = 0; i2 < 4; i2++) {
    float4 o;
    o.x = acc[i2][0] + bb[0];
    o.y = acc[i2][1] + bb[1];
    o.z = acc[i2][2] + bb[2];
    o.w = acc[i2][3] + bb[3];
    *(float4*)(Co + (size_t)(m0 + ty * 4 + i2) * RR + n0 + tx * 4) = o;
  }
}

// ---------- lateral: lat[b,:] = sum over spiking k of WlT[k,:] (sparse gather) ----------
__global__ __launch_bounds__(256) void k_lateral(const float* __restrict__ spike,
                                                 const float* __restrict__ WlT,
                                                 float* __restrict__ lat) {
  __shared__ int idx[2048];
  __shared__ int wcnt[4];
  int tid = threadIdx.x;
  int lane = tid & 63;
  int wv = tid >> 6;
  int b = blockIdx.y;
  int chunk = blockIdx.x;
  const float* sp = spike + (size_t)b * RR;
  int total = 0;
  // deterministic ascending-k compaction of spike indices
  for (int c = 0; c < RR / 256; c++) {
    int k = c * 256 + tid;
    bool f = sp[k] > 0.5f;
    unsigned long long bal = __ballot(f);
    int wc = __popcll(bal);
    int pre = __popcll(bal & ((1ull << lane) - 1ull));
    if (lane == 0) wcnt[wv] = wc;
    __syncthreads();
    int base = total;
    int w0 = wcnt[0], w1 = wcnt[1], w2 = wcnt[2], w3 = wcnt[3];
    if (wv > 0) base += w0;
    if (wv > 1) base += w1;
    if (wv > 2) base += w2;
    if (f) {
      int p = base + pre;
      if (p < 2048) idx[p] = k;
    }
    total += w0 + w1 + w2 + w3;
    __syncthreads();
  }
  int M = total > 2048 ? 2048 : total;  // bound: <=1025 by WTA construction
  int n0 = chunk * 512;
  float2 acc = make_float2(0.f, 0.f);
  int s = 0;
  for (; s + 4 <= M; s += 4) {
    int k0 = idx[s], k1 = idx[s + 1], k2 = idx[s + 2], k3 = idx[s + 3];
    float2 v0 = *(const float2*)(WlT + (size_t)k0 * RR + n0 + 2 * tid);
    float2 v1 = *(const float2*)(WlT + (size_t)k1 * RR + n0 + 2 * tid);
    float2 v2 = *(const float2*)(WlT + (size_t)k2 * RR + n0 + 2 * tid);
    float2 v3 = *(const float2*)(WlT + (size_t)k3 * RR + n0 + 2 * tid);
    acc.x += v0.x; acc.y += v0.y;
    acc.x += v1.x; acc.y += v1.y;
    acc.x += v2.x; acc.y += v2.y;
    acc.x += v3.x; acc.y += v3.y;
  }
  for (; s < M; s++) {
    float2 v0 = *(const float2*)(WlT + (size_t)idx[s] * RR + n0 + 2 * tid);
    acc.x += v0.x; acc.y += v0.y;
  }
  *(float2*)(lat + (size_t)b * RR + n0 + 2 * tid) = acc;
}

// ---------- LIF update + WTA quantile (group = r mod 5) + spike + traces ----------
__global__ __launch_bounds__(256) void k_wta(const float* __restrict__ drv,
                                             const float* __restrict__ lat,
                                             const float* __restrict__ bl,
                                             const float* __restrict__ dec_,
                                             const float* __restrict__ tb_,
                                             const float* __restrict__ td_,
                                             const float* __restrict__ rb_,
                                             const float* __restrict__ rd_,
                                             const float* __restrict__ cb_,
                                             const float* __restrict__ cd_,
                                             float* __restrict__ spike,
                                             float* __restrict__ memv,
                                             float* __restrict__ ttr,
                                             float* __restrict__ rtr,
                                             float* __restrict__ ctr,
                                             float* __restrict__ ssum) {
  __shared__ float sv[1024];
  int tid = threadIdx.x;
  int b = blockIdx.x / NB;
  int j = blockIdx.x % NB;
  float m_new[4], thv[4], tt[4], tr[4], tc[4];
#pragma unroll
  for (int p = 0; p < 4; p++) {
    int i = p * 256 + tid;
    int r = i * NB + j;  // torch row-major reshape: group j = {r : r % 5 == j}
    size_t br = (size_t)b * RR + r;
    float sp = spike[br];
    float t_t = ttr[br], t_r = rtr[br], t_c = ctr[br];
    float th = 0.5f + tb_[r] * t_t;
    float rf = 0.5f + rb_[r] * t_r;
    float cu = cb_[r] * t_c;
    float dc = fminf(fmaxf(dec_[r], 0.f), 1.f);
    float st = drv[br] + lat[br] + bl[r];
    float mn = (memv[br] - sp * rf) * dc + st + cu;
    m_new[p] = mn; thv[p] = th; tt[p] = t_t; tr[p] = t_r; tc[p] = t_c;
    sv[i] = mn;
  }
  // bitonic sort ascending, 1024 elements
  for (int k = 2; k <= 1024; k <<= 1) {
    for (int jj = k >> 1; jj > 0; jj >>= 1) {
      __syncthreads();
#pragma unroll
      for (int p = 0; p < 4; p++) {
        int t2 = p * 256 + tid;
        int partner = t2 ^ jj;
        if (partner > t2) {
          bool up = ((t2 & k) == 0);
          float a = sv[t2], b2 = sv[partner];
          if ((a > b2) == up) { sv[t2] = b2; sv[partner] = a; }
        }
      }
    }
  }
  __syncthreads();
  float v818 = sv[818], v819 = sv[819];
  float frac = 0.8f * 1023.0f - 818.0f;  // jnp.quantile linear interp, f32
  float nps = v818 + frac * (v819 - v818);
#pragma unroll
  for (int p = 0; p < 4; p++) {
    int i = p * 256 + tid;
    int r = i * NB + j;
    size_t br = (size_t)b * RR + r;
    float mw = fmaxf(m_new[p] - nps, 0.f);
    float sk = (mw - thv[p] > 0.f) ? 1.f : 0.f;
    float td = fminf(fmaxf(td_[r], 0.f), 1.f);
    float rd = fminf(fmaxf(rd_[r], 0.f), 1.f);
    float cd = fminf(fmaxf(cd_[r], 0.f), 1.f);
    memv[br] = mw;
    spike[br] = sk;
    ttr[br] = tt[p] * td + sk;
    rtr[br] = tr[p] * rd + sk;
    ctr[br] = tc[p] * cd + sk;
    ssum[br] += sk;
  }
}

// ---------- readout: out = (ssum/24) @ Wm^T + bm ----------
__global__ __launch_bounds__(256) void k_readout(const float* __restrict__ ssum,
                                                 const float* __restrict__ Wm,
                                                 const float* __restrict__ bm,
                                                 float* __restrict__ out) {
  __shared__ float ss[RR];
  int tid = threadIdx.x;
  int b = blockIdx.x;
  for (int i = tid; i < RR; i += 256) ss[i] = ssum[(size_t)b * RR + i];
  __syncthreads();
  int wv = tid >> 6, lane = tid & 63;
  for (int c = wv; c < CC; c += 4) {
    const float* wr = Wm + (size_t)c * RR;
    float acc = 0.f;
    for (int k = lane; k < RR; k += 64) acc += ss[k] * wr[k];
    for (int o = 32; o > 0; o >>= 1) acc += __shfl_down(acc, o, 64);
    if (lane == 0) out[b * CC + c] = acc * (1.0f / 24.0f) + bm[c];
  }
}

extern "C" void kernel_launch(void* const* d_in, const int* in_sizes, int n_in,
                              void* d_out, int out_size, void* d_ws, size_t ws_size,
                              hipStream_t stream) {
  const float* x = (const float*)d_in[0];
  const float* ln_g = (const float*)d_in[1];
  const float* ln_b = (const float*)d_in[2];
  const float* Wp = (const float*)d_in[3];
  const float* bp = (const float*)d_in[4];
  const float* Wl = (const float*)d_in[5];
  const float* bl = (const float*)d_in[6];
  const float* Wm = (const float*)d_in[7];
  const float* bm = (const float*)d_in[8];
  const float* decay = (const float*)d_in[9];
  const float* thr_beta = (const float*)d_in[10];
  const float* thr_decay = (const float*)d_in[11];
  const float* ref_beta = (const float*)d_in[12];
  const float* ref_decay = (const float*)d_in[13];
  const float* cur_beta = (const float*)d_in[14];
  const float* cur_decay = (const float*)d_in[15];
  const float* proj_mask = (const float*)d_in[16];
  const float* lat_mask = (const float*)d_in[17];
  float* out = (float*)d_out;

  float* ws = (float*)d_ws;
  float* WlT = ws;                             // R*R
  float* Wpm = WlT + (size_t)RR * RR;          // R*D
  float* xn = Wpm + (size_t)RR * DD;           // T*B*D
  float* drive = xn + (size_t)TSTEPS * BB * DD;// T*B*R
  float* lat = drive + (size_t)TSTEPS * BB * RR;
  float* spike = lat + (size_t)BB * RR;
  float* memv = spike + (size_t)BB * RR;
  float* ttr = memv + (size_t)BB * RR;
  float* rtr = ttr + (size_t)BB * RR;
  float* ctr = rtr + (size_t)BB * RR;
  float* ssum = ctr + (size_t)BB * RR;
  // total ws use: ~186.4 MB

  hipLaunchKernelGGL(k_prep, dim3(2048), dim3(256), 0, stream, Wp, proj_mask, Wpm, spike);
  hipLaunchKernelGGL(k_transpose, dim3(RR / 32, RR / 32), dim3(32, 8), 0, stream,
                     Wl, lat_mask, WlT);
  hipLaunchKernelGGL(k_layernorm, dim3(TSTEPS * BB), dim3(256), 0, stream,
                     x, ln_g, ln_b, xn);
  hipLaunchKernelGGL(k_gemm_drive, dim3(RR / 64, TSTEPS * BB / 64), dim3(256), 0, stream,
                     xn, Wpm, bp, drive);
  for (int t = 0; t < TSTEPS; t++) {
    hipLaunchKernelGGL(k_lateral, dim3(RR / 512, BB), dim3(256), 0, stream,
                       spike, WlT, lat);
    hipLaunchKernelGGL(k_wta, dim3(BB * NB), dim3(256), 0, stream,
                       drive + (size_t)t * BB * RR, lat, bl,
                       decay, thr_beta, thr_decay, ref_beta, ref_decay,
                       cur_beta, cur_decay,
                       spike, memv, ttr, rtr, ctr, ssum);
  }
  hipLaunchKernelGGL(k_readout, dim3(BB), dim3(256), 0, stream, ssum, Wm, bm, out);
}

// Round 2
// 2055.250 us; speedup vs baseline: 1.3281x; 1.3281x over previous
//
#include <hip/hip_runtime.h>
#include <math.h>

#define TSTEPS 24
#define BB 64
#define DD 1536
#define RR 5120
#define NB 5
#define CC 100

// ---------- prep: Wp_m = Wp * proj_mask ; zero state buffers + spike-list counts ----------
__global__ __launch_bounds__(256) void k_prep(const float* __restrict__ Wp,
                                              const float* __restrict__ pm,
                                              float* __restrict__ Wpm,
                                              float* __restrict__ zbuf,
                                              int* __restrict__ cntg) {
  size_t n = (size_t)RR * DD;
  size_t zn = 6ull * BB * RR;
  size_t gi0 = (size_t)blockIdx.x * 256 + threadIdx.x;
  if (gi0 < BB * NB) cntg[gi0] = 0;
  for (size_t i = gi0; i < n; i += (size_t)gridDim.x * 256) {
    Wpm[i] = Wp[i] * pm[i];
    if (i < zn) zbuf[i] = 0.0f;
  }
}

// ---------- WlT[k][r] = Wl[r][k] * lat_mask[r][k] (masked transpose) ----------
__global__ __launch_bounds__(256) void k_transpose(const float* __restrict__ Wl,
                                                   const float* __restrict__ lm,
                                                   float* __restrict__ WlT) {
  __shared__ float tile[32][33];
  int k0 = blockIdx.x * 32;
  int r0 = blockIdx.y * 32;
  int tx = threadIdx.x;  // 0..31
  int ty = threadIdx.y;  // 0..7
  for (int i = ty; i < 32; i += 8) {
    size_t src = (size_t)(r0 + i) * RR + (k0 + tx);
    tile[i][tx] = Wl[src] * lm[src];
  }
  __syncthreads();
  for (int i = ty; i < 32; i += 8) {
    WlT[(size_t)(k0 + i) * RR + (r0 + tx)] = tile[tx][i];
  }
}

// ---------- LayerNorm over D=1536, one block per (t,b) row ----------
__global__ __launch_bounds__(256) void k_layernorm(const float* __restrict__ x,
                                                   const float* __restrict__ g,
                                                   const float* __restrict__ be,
                                                   float* __restrict__ xn) {
  __shared__ float red[4];
  int row = blockIdx.x;
  int tid = threadIdx.x;
  const float* xr = x + (size_t)row * DD;
  float v[6];
  float s = 0.f;
#pragma unroll
  for (int i = 0; i < 6; i++) { v[i] = xr[i * 256 + tid]; s += v[i]; }
  for (int o = 32; o > 0; o >>= 1) s += __shfl_down(s, o, 64);
  int wv = tid >> 6, lane = tid & 63;
  if (lane == 0) red[wv] = s;
  __syncthreads();
  float mu = (red[0] + red[1] + red[2] + red[3]) * (1.0f / DD);
  __syncthreads();
  float sq = 0.f;
#pragma unroll
  for (int i = 0; i < 6; i++) { float d = v[i] - mu; sq += d * d; }
  for (int o = 32; o > 0; o >>= 1) sq += __shfl_down(sq, o, 64);
  if (lane == 0) red[wv] = sq;
  __syncthreads();
  float var = (red[0] + red[1] + red[2] + red[3]) * (1.0f / DD);
  float sc = 1.0f / sqrtf(var + 1e-5f);
#pragma unroll
  for (int i = 0; i < 6; i++) {
    int c = i * 256 + tid;
    xn[(size_t)row * DD + c] = (v[i] - mu) * sc * g[c] + be[c];
  }
}

// ---------- drive = xn @ Wp_m^T + bp  (f32, 64x64 tile, 4x4 microtile) ----------
__global__ __launch_bounds__(256) void k_gemm_drive(const float* __restrict__ A,
                                                    const float* __restrict__ Bw,
                                                    const float* __restrict__ bp,
                                                    float* __restrict__ Co) {
  __shared__ __align__(16) float As[16][68];
  __shared__ __align__(16) float Bs[16][68];
  int tid = threadIdx.x;
  int m0 = blockIdx.y * 64;
  int n0 = blockIdx.x * 64;
  int lr = tid >> 2;  // 0..63 row in tile
  int lq = tid & 3;   // 0..3 k-quad
  int tx = tid & 15;
  int ty = tid >> 4;
  float acc[4][4] = {};
  const float4* Arow = (const float4*)(A + (size_t)(m0 + lr) * DD);
  const float4* Brow = (const float4*)(Bw + (size_t)(n0 + lr) * DD);
  for (int k0 = 0; k0 < DD; k0 += 16) {
    float4 av = Arow[(k0 >> 2) + lq];
    float4 bv = Brow[(k0 >> 2) + lq];
    __syncthreads();
    As[lq * 4 + 0][lr] = av.x; As[lq * 4 + 1][lr] = av.y;
    As[lq * 4 + 2][lr] = av.z; As[lq * 4 + 3][lr] = av.w;
    Bs[lq * 4 + 0][lr] = bv.x; Bs[lq * 4 + 1][lr] = bv.y;
    Bs[lq * 4 + 2][lr] = bv.z; Bs[lq * 4 + 3][lr] = bv.w;
    __syncthreads();
#pragma unroll
    for (int kk = 0; kk < 16; kk++) {
      float4 a4 = *(const float4*)&As[kk][ty * 4];
      float4 b4 = *(const float4*)&Bs[kk][tx * 4];
      float av2[4] = {a4.x, a4.y, a4.z, a4.w};
      float bv2[4] = {b4.x, b4.y, b4.z, b4.w};
#pragma unroll
      for (int i2 = 0; i2 < 4; i2++)
#pragma unroll
        for (int j2 = 0; j2 < 4; j2++) acc[i2][j2] += av2[i2] * bv2[j2];
    }
  }
  float bb[4];
#pragma unroll
  for (int j2 = 0; j2 < 4; j2++) bb[j2] = bp[n0 + tx * 4 + j2];
#pragma unroll
  for (int i2 = 0; i2 < 4; i2++) {
    float4 o;
    o.x = acc[i2][0] + bb[0];
    o.y = acc[i2][1] + bb[1];
    o.z = acc[i2][2] + bb[2];
    o.w = acc[i2][3] + bb[3];
    *(float4*)(Co + (size_t)(m0 + ty * 4 + i2) * RR + n0 + tx * 4) = o;
  }
}

// ---------- lateral: lat[b, n0:n0+1024] = sum over spiking k of WlT[k, ...] ----------
// spike lists come pre-compacted per (b, j-group) from k_wta's epilogue.
__global__ __launch_bounds__(256) void k_lateral(const int* __restrict__ idxg,
                                                 const int* __restrict__ cntg,
                                                 const float* __restrict__ WlT,
                                                 float* __restrict__ lat) {
  __shared__ int sidx[NB * 256];
  __shared__ int soff[NB + 1];
  int tid = threadIdx.x;
  int b = blockIdx.y;
  int n0 = blockIdx.x * 1024;
  if (tid == 0) {
    int o = 0;
#pragma unroll
    for (int jj = 0; jj < NB; jj++) { soff[jj] = o; o += cntg[b * NB + jj]; }
    soff[NB] = o;
  }
  __syncthreads();
#pragma unroll
  for (int jj = 0; jj < NB; jj++) {
    int o = soff[jj], nn = soff[jj + 1] - o;
    for (int i = tid; i < nn; i += 256) sidx[o + i] = idxg[(b * NB + jj) * 256 + i];
  }
  __syncthreads();
  int M = soff[NB];
  const float* base = WlT + n0 + 4 * tid;
  float4 acc = make_float4(0.f, 0.f, 0.f, 0.f);
  int s = 0;
  for (; s + 4 <= M; s += 4) {
    int k0 = sidx[s], k1 = sidx[s + 1], k2 = sidx[s + 2], k3 = sidx[s + 3];
    float4 v0 = *(const float4*)(base + (size_t)k0 * RR);
    float4 v1 = *(const float4*)(base + (size_t)k1 * RR);
    float4 v2 = *(const float4*)(base + (size_t)k2 * RR);
    float4 v3 = *(const float4*)(base + (size_t)k3 * RR);
    acc.x += v0.x; acc.y += v0.y; acc.z += v0.z; acc.w += v0.w;
    acc.x += v1.x; acc.y += v1.y; acc.z += v1.z; acc.w += v1.w;
    acc.x += v2.x; acc.y += v2.y; acc.z += v2.z; acc.w += v2.w;
    acc.x += v3.x; acc.y += v3.y; acc.z += v3.z; acc.w += v3.w;
  }
  for (; s < M; s++) {
    float4 v0 = *(const float4*)(base + (size_t)sidx[s] * RR);
    acc.x += v0.x; acc.y += v0.y; acc.z += v0.z; acc.w += v0.w;
  }
  *(float4*)(lat + (size_t)b * RR + n0 + 4 * tid) = acc;
}

// ---------- LIF update + WTA quantile (group = r mod 5) + spike + traces + compact ----------
__global__ __launch_bounds__(256) void k_wta(const float* __restrict__ drv,
                                             const float* __restrict__ lat,
                                             const float* __restrict__ bl,
                                             const float* __restrict__ dec_,
                                             const float* __restrict__ tb_,
                                             const float* __restrict__ td_,
                                             const float* __restrict__ rb_,
                                             const float* __restrict__ rd_,
                                             const float* __restrict__ cb_,
                                             const float* __restrict__ cd_,
                                             float* __restrict__ spike,
                                             float* __restrict__ memv,
                                             float* __restrict__ ttr,
                                             float* __restrict__ rtr,
                                             float* __restrict__ ctr,
                                             float* __restrict__ ssum,
                                             int* __restrict__ idxg,
                                             int* __restrict__ cntg) {
  __shared__ float sv[1024];
  __shared__ int wcnt[4];
  int tid = threadIdx.x;
  int lane = tid & 63;
  int wv = tid >> 6;
  int b = blockIdx.x / NB;
  int j = blockIdx.x % NB;
  float m_new[4], thv[4], tt[4], tr[4], tc[4];
#pragma unroll
  for (int p = 0; p < 4; p++) {
    int i = p * 256 + tid;
    int r = i * NB + j;  // torch row-major reshape: group j = {r : r % 5 == j}
    size_t br = (size_t)b * RR + r;
    float sp = spike[br];
    float t_t = ttr[br], t_r = rtr[br], t_c = ctr[br];
    float th = 0.5f + tb_[r] * t_t;
    float rf = 0.5f + rb_[r] * t_r;
    float cu = cb_[r] * t_c;
    float dc = fminf(fmaxf(dec_[r], 0.f), 1.f);
    float st = drv[br] + lat[br] + bl[r];
    float mn = (memv[br] - sp * rf) * dc + st + cu;
    m_new[p] = mn; thv[p] = th; tt[p] = t_t; tr[p] = t_r; tc[p] = t_c;
    sv[i] = mn;
  }
  // bitonic sort ascending, 1024 elements
  for (int k = 2; k <= 1024; k <<= 1) {
    for (int jj = k >> 1; jj > 0; jj >>= 1) {
      __syncthreads();
#pragma unroll
      for (int p = 0; p < 4; p++) {
        int t2 = p * 256 + tid;
        int partner = t2 ^ jj;
        if (partner > t2) {
          bool up = ((t2 & k) == 0);
          float a = sv[t2], b2 = sv[partner];
          if ((a > b2) == up) { sv[t2] = b2; sv[partner] = a; }
        }
      }
    }
  }
  __syncthreads();
  float v818 = sv[818], v819 = sv[819];
  float frac = 0.8f * 1023.0f - 818.0f;  // jnp.quantile linear interp, f32
  float nps = v818 + frac * (v819 - v818);
  int total = 0;
#pragma unroll
  for (int p = 0; p < 4; p++) {
    int i = p * 256 + tid;
    int r = i * NB + j;
    size_t br = (size_t)b * RR + r;
    float mw = fmaxf(m_new[p] - nps, 0.f);
    float sk = (mw - thv[p] > 0.f) ? 1.f : 0.f;
    float td = fminf(fmaxf(td_[r], 0.f), 1.f);
    float rd = fminf(fmaxf(rd_[r], 0.f), 1.f);
    float cd = fminf(fmaxf(cd_[r], 0.f), 1.f);
    memv[br] = mw;
    spike[br] = sk;
    ttr[br] = tt[p] * td + sk;
    rtr[br] = tr[p] * rd + sk;
    ctr[br] = tc[p] * cd + sk;
    ssum[br] += sk;
    // ---- deterministic ascending-r compaction of this group's spikes ----
    bool f = sk > 0.5f;
    unsigned long long bal = __ballot(f);
    if (lane == 0) wcnt[wv] = __popcll(bal);
    __syncthreads();
    int base = total;
    if (wv > 0) base += wcnt[0];
    if (wv > 1) base += wcnt[1];
    if (wv > 2) base += wcnt[2];
    int pre = __popcll(bal & ((1ull << lane) - 1ull));
    if (f) {
      int pp = base + pre;
      if (pp < 256) idxg[(b * NB + j) * 256 + pp] = r;  // WTA bounds spikes/group <= 205
    }
    total += wcnt[0] + wcnt[1] + wcnt[2] + wcnt[3];
    __syncthreads();
  }
  if (tid == 0) cntg[b * NB + j] = total > 256 ? 256 : total;
}

// ---------- readout: out[b,c] = dot(ssum[b,:], Wm[c,:])/24 + bm[c] ----------
__global__ __launch_bounds__(256) void k_readout(const float* __restrict__ ssum,
                                                 const float* __restrict__ Wm,
                                                 const float* __restrict__ bm,
                                                 float* __restrict__ out) {
  __shared__ float red[4];
  int c = blockIdx.x;
  int b = blockIdx.y;
  int tid = threadIdx.x;
  const float4* sp = (const float4*)(ssum + (size_t)b * RR);
  const float4* wp = (const float4*)(Wm + (size_t)c * RR);
  float acc = 0.f;
#pragma unroll
  for (int i = 0; i < 5; i++) {  // 5120/4 = 1280 = 5*256
    float4 s4 = sp[i * 256 + tid];
    float4 w4 = wp[i * 256 + tid];
    acc += s4.x * w4.x + s4.y * w4.y + s4.z * w4.z + s4.w * w4.w;
  }
  for (int o = 32; o > 0; o >>= 1) acc += __shfl_down(acc, o, 64);
  if ((tid & 63) == 0) red[tid >> 6] = acc;
  __syncthreads();
  if (tid == 0)
    out[b * CC + c] = (red[0] + red[1] + red[2] + red[3]) * (1.0f / 24.0f) + bm[c];
}

extern "C" void kernel_launch(void* const* d_in, const int* in_sizes, int n_in,
                              void* d_out, int out_size, void* d_ws, size_t ws_size,
                              hipStream_t stream) {
  const float* x = (const float*)d_in[0];
  const float* ln_g = (const float*)d_in[1];
  const float* ln_b = (const float*)d_in[2];
  const float* Wp = (const float*)d_in[3];
  const float* bp = (const float*)d_in[4];
  const float* Wl = (const float*)d_in[5];
  const float* bl = (const float*)d_in[6];
  const float* Wm = (const float*)d_in[7];
  const float* bm = (const float*)d_in[8];
  const float* decay = (const float*)d_in[9];
  const float* thr_beta = (const float*)d_in[10];
  const float* thr_decay = (const float*)d_in[11];
  const float* ref_beta = (const float*)d_in[12];
  const float* ref_decay = (const float*)d_in[13];
  const float* cur_beta = (const float*)d_in[14];
  const float* cur_decay = (const float*)d_in[15];
  const float* proj_mask = (const float*)d_in[16];
  const float* lat_mask = (const float*)d_in[17];
  float* out = (float*)d_out;

  float* ws = (float*)d_ws;
  float* WlT = ws;                              // R*R
  float* Wpm = WlT + (size_t)RR * RR;           // R*D
  float* xn = Wpm + (size_t)RR * DD;            // T*B*D
  float* drive = xn + (size_t)TSTEPS * BB * DD; // T*B*R
  float* lat = drive + (size_t)TSTEPS * BB * RR;
  float* spike = lat + (size_t)BB * RR;
  float* memv = spike + (size_t)BB * RR;
  float* ttr = memv + (size_t)BB * RR;
  float* rtr = ttr + (size_t)BB * RR;
  float* ctr = rtr + (size_t)BB * RR;
  float* ssum = ctr + (size_t)BB * RR;
  int* idxg = (int*)(ssum + (size_t)BB * RR);   // B*NB*256 ints
  int* cntg = idxg + BB * NB * 256;             // B*NB ints

  hipLaunchKernelGGL(k_prep, dim3(2048), dim3(256), 0, stream, Wp, proj_mask, Wpm,
                     spike, cntg);
  hipLaunchKernelGGL(k_transpose, dim3(RR / 32, RR / 32), dim3(32, 8), 0, stream,
                     Wl, lat_mask, WlT);
  hipLaunchKernelGGL(k_layernorm, dim3(TSTEPS * BB), dim3(256), 0, stream,
                     x, ln_g, ln_b, xn);
  hipLaunchKernelGGL(k_gemm_drive, dim3(RR / 64, TSTEPS * BB / 64), dim3(256), 0, stream,
                     xn, Wpm, bp, drive);
  for (int t = 0; t < TSTEPS; t++) {
    hipLaunchKernelGGL(k_lateral, dim3(RR / 1024, BB), dim3(256), 0, stream,
                       idxg, cntg, WlT, lat);
    hipLaunchKernelGGL(k_wta, dim3(BB * NB), dim3(256), 0, stream,
                       drive + (size_t)t * BB * RR, lat, bl,
                       decay, thr_beta, thr_decay, ref_beta, ref_decay,
                       cur_beta, cur_decay,
                       spike, memv, ttr, rtr, ctr, ssum, idxg, cntg);
  }
  hipLaunchKernelGGL(k_readout, dim3(CC, BB), dim3(256), 0, stream, ssum, Wm, bm, out);
}

// Round 3
// 1448.380 us; speedup vs baseline: 1.8845x; 1.4190x over previous
//
#include <hip/hip_runtime.h>
#include <math.h>

#define TSTEPS 24
#define BB 64
#define DD 1536
#define RR 5120
#define NB 5
#define CC 100

// q-layout: q = j*1024 + i  <->  r = i*5 + j   (j = r%5 group, i = r/5)
__device__ __forceinline__ int q_to_r(int q) { return (q & 1023) * 5 + (q >> 10); }

// monotone f32 <-> uint key transform
__device__ __forceinline__ unsigned fkey(float f) {
  unsigned u = __float_as_uint(f);
  return u ^ (((unsigned)((int)u >> 31)) | 0x80000000u);
}
__device__ __forceinline__ float fkeyinv(unsigned k) {
  unsigned u = (k & 0x80000000u) ? (k ^ 0x80000000u) : ~k;
  return __uint_as_float(u);
}

// ---------- zero state buffers + list counts ----------
__global__ __launch_bounds__(256) void k_zero(float* __restrict__ state,
                                              int* __restrict__ cnt) {
  size_t n = 6ull * BB * RR;
  size_t gi = (size_t)blockIdx.x * 256 + threadIdx.x;
  if (gi < 2 * BB * NB) cnt[gi] = 0;
  for (size_t i = gi; i < n; i += (size_t)gridDim.x * 256) state[i] = 0.0f;
}

// ---------- permute per-neuron params into q-layout; fold bp+bl; pre-clamp ----------
__global__ __launch_bounds__(256) void k_prep_params(
    const float* __restrict__ bp, const float* __restrict__ bl,
    const float* __restrict__ dec, const float* __restrict__ tb,
    const float* __restrict__ td, const float* __restrict__ rb,
    const float* __restrict__ rd, const float* __restrict__ cb,
    const float* __restrict__ cd, float* __restrict__ P) {
  int q = blockIdx.x * 256 + threadIdx.x;
  if (q >= RR) return;
  int r = q_to_r(q);
  P[0 * RR + q] = bp[r] + bl[r];
  P[1 * RR + q] = fminf(fmaxf(dec[r], 0.f), 1.f);
  P[2 * RR + q] = tb[r];
  P[3 * RR + q] = fminf(fmaxf(td[r], 0.f), 1.f);
  P[4 * RR + q] = rb[r];
  P[5 * RR + q] = fminf(fmaxf(rd[r], 0.f), 1.f);
  P[6 * RR + q] = cb[r];
  P[7 * RR + q] = fminf(fmaxf(cd[r], 0.f), 1.f);
}

// ---------- Wm_p[c][q] = Wm[c][r(q)] ----------
__global__ __launch_bounds__(256) void k_prep_wm(const float* __restrict__ Wm,
                                                 float* __restrict__ Wmp) {
  int c = blockIdx.x;
  for (int q = threadIdx.x; q < RR; q += 256)
    Wmp[(size_t)c * RR + q] = Wm[(size_t)c * RR + q_to_r(q)];
}

// ---------- Wpm_p[q][d] = Wp[r(q)][d] * pm[r(q)][d]  (row permute, coalesced) ----------
__global__ __launch_bounds__(256) void k_prep_wpm(const float* __restrict__ Wp,
                                                  const float* __restrict__ pm,
                                                  float* __restrict__ Wpm) {
  int q = blockIdx.x;
  int r = q_to_r(q);
  const float* src = Wp + (size_t)r * DD;
  const float* msk = pm + (size_t)r * DD;
  float* dst = Wpm + (size_t)q * DD;
  for (int c = threadIdx.x; c < DD; c += 256) dst[c] = src[c] * msk[c];
}

// ---------- WlT_p[k][q(r)] = Wl[r][k] * lat_mask[r][k]  (masked transpose + col permute) ----------
__global__ __launch_bounds__(256) void k_transpose_p(const float* __restrict__ Wl,
                                                     const float* __restrict__ lm,
                                                     float* __restrict__ WlTp) {
  __shared__ float tile[160][33];
  int k0 = blockIdx.x * 32;
  int r0 = blockIdx.y * 160;  // multiple of 5
  int tx = threadIdx.x;       // 0..31
  int ty = threadIdx.y;       // 0..7
  for (int l = ty; l < 160; l += 8) {
    size_t src = (size_t)(r0 + l) * RR + (k0 + tx);
    tile[l][tx] = Wl[src] * lm[src];
  }
  __syncthreads();
  int ibase = r0 / 5;
  for (int ii = ty; ii < 32; ii += 8) {
#pragma unroll
    for (int j5 = 0; j5 < NB; j5++) {
      WlTp[(size_t)(k0 + ii) * RR + j5 * 1024 + ibase + tx] = tile[tx * 5 + j5][ii];
    }
  }
}

// ---------- LayerNorm over D=1536, one block per (t,b) row ----------
__global__ __launch_bounds__(256) void k_layernorm(const float* __restrict__ x,
                                                   const float* __restrict__ g,
                                                   const float* __restrict__ be,
                                                   float* __restrict__ xn) {
  __shared__ float red[4];
  int row = blockIdx.x;
  int tid = threadIdx.x;
  const float* xr = x + (size_t)row * DD;
  float v[6];
  float s = 0.f;
#pragma unroll
  for (int i = 0; i < 6; i++) { v[i] = xr[i * 256 + tid]; s += v[i]; }
  for (int o = 32; o > 0; o >>= 1) s += __shfl_down(s, o, 64);
  int wv = tid >> 6, lane = tid & 63;
  if (lane == 0) red[wv] = s;
  __syncthreads();
  float mu = (red[0] + red[1] + red[2] + red[3]) * (1.0f / DD);
  __syncthreads();
  float sq = 0.f;
#pragma unroll
  for (int i = 0; i < 6; i++) { float d = v[i] - mu; sq += d * d; }
  for (int o = 32; o > 0; o >>= 1) sq += __shfl_down(sq, o, 64);
  if (lane == 0) red[wv] = sq;
  __syncthreads();
  float var = (red[0] + red[1] + red[2] + red[3]) * (1.0f / DD);
  float sc = 1.0f / sqrtf(var + 1e-5f);
#pragma unroll
  for (int i = 0; i < 6; i++) {
    int c = i * 256 + tid;
    xn[(size_t)row * DD + c] = (v[i] - mu) * sc * g[c] + be[c];
  }
}

// ---------- drive = xn @ Wpm_p^T + (bp+bl)  (f32, 64x64 tile, 4x4 microtile) ----------
__global__ __launch_bounds__(256) void k_gemm_drive(const float* __restrict__ A,
                                                    const float* __restrict__ Bw,
                                                    const float* __restrict__ bias,
                                                    float* __restrict__ Co) {
  __shared__ __align__(16) float As[16][68];
  __shared__ __align__(16) float Bs[16][68];
  int tid = threadIdx.x;
  int m0 = blockIdx.y * 64;
  int n0 = blockIdx.x * 64;
  int lr = tid >> 2;
  int lq = tid & 3;
  int tx = tid & 15;
  int ty = tid >> 4;
  float acc[4][4] = {};
  const float4* Arow = (const float4*)(A + (size_t)(m0 + lr) * DD);
  const float4* Brow = (const float4*)(Bw + (size_t)(n0 + lr) * DD);
  for (int k0 = 0; k0 < DD; k0 += 16) {
    float4 av = Arow[(k0 >> 2) + lq];
    float4 bv = Brow[(k0 >> 2) + lq];
    __syncthreads();
    As[lq * 4 + 0][lr] = av.x; As[lq * 4 + 1][lr] = av.y;
    As[lq * 4 + 2][lr] = av.z; As[lq * 4 + 3][lr] = av.w;
    Bs[lq * 4 + 0][lr] = bv.x; Bs[lq * 4 + 1][lr] = bv.y;
    Bs[lq * 4 + 2][lr] = bv.z; Bs[lq * 4 + 3][lr] = bv.w;
    __syncthreads();
#pragma unroll
    for (int kk = 0; kk < 16; kk++) {
      float4 a4 = *(const float4*)&As[kk][ty * 4];
      float4 b4 = *(const float4*)&Bs[kk][tx * 4];
      float av2[4] = {a4.x, a4.y, a4.z, a4.w};
      float bv2[4] = {b4.x, b4.y, b4.z, b4.w};
#pragma unroll
      for (int i2 = 0; i2 < 4; i2++)
#pragma unroll
        for (int j2 = 0; j2 < 4; j2++) acc[i2][j2] += av2[i2] * bv2[j2];
    }
  }
  float bb[4];
#pragma unroll
  for (int j2 = 0; j2 < 4; j2++) bb[j2] = bias[n0 + tx * 4 + j2];
#pragma unroll
  for (int i2 = 0; i2 < 4; i2++) {
    float4 o;
    o.x = acc[i2][0] + bb[0];
    o.y = acc[i2][1] + bb[1];
    o.z = acc[i2][2] + bb[2];
    o.w = acc[i2][3] + bb[3];
    *(float4*)(Co + (size_t)(m0 + ty * 4 + i2) * RR + n0 + tx * 4) = o;
  }
}

// ---------- fused step: sparse lateral gather + LIF + radix-select WTA + update + compact ----------
__global__ __launch_bounds__(256) void k_step(
    const float* __restrict__ drv_t,   // drive + t*B*R   (q-layout cols)
    const float* __restrict__ WlTp,    // [k][q]
    const float* __restrict__ P,       // 8 param vectors, q-layout
    float* __restrict__ spike, float* __restrict__ memv,
    float* __restrict__ ttr, float* __restrict__ rtr, float* __restrict__ ctr,
    float* __restrict__ ssum,
    const int* __restrict__ idx_in, const int* __restrict__ cnt_in,
    int* __restrict__ idx_out, int* __restrict__ cnt_out) {
  __shared__ int slist[1280];
  __shared__ int soff[NB + 1];
  __shared__ unsigned hist[256];
  __shared__ unsigned wtot[4];
  __shared__ unsigned s_prefix, s_rank, s_cle, s_min;

  int tid = threadIdx.x;
  int lane = tid & 63;
  int wv = tid >> 6;
  int j = blockIdx.x;
  int b = blockIdx.y;

  // 1. load all spike lists of batch b (offsets premultiplied by RR)
  if (tid == 0) {
    int o = 0;
#pragma unroll
    for (int jj = 0; jj < NB; jj++) { soff[jj] = o; o += cnt_in[b * NB + jj]; }
    soff[NB] = o;
    s_prefix = 0u; s_rank = 818u; s_cle = 0u; s_min = 0xFFFFFFFFu;
  }
  __syncthreads();
#pragma unroll
  for (int jj = 0; jj < NB; jj++) {
    int o = soff[jj], n = soff[jj + 1] - o;
    for (int i = tid; i < n; i += 256) slist[o + i] = idx_in[(b * NB + jj) * 256 + i];
  }
  __syncthreads();
  int M = soff[NB];

  // 2. gather lateral contribution for my 4 columns
  const float* gbase = WlTp + j * 1024 + 4 * tid;
  float4 acc = make_float4(0.f, 0.f, 0.f, 0.f);
  int s = 0;
  for (; s + 4 <= M; s += 4) {
    int o0 = slist[s], o1 = slist[s + 1], o2 = slist[s + 2], o3 = slist[s + 3];
    float4 v0 = *(const float4*)(gbase + o0);
    float4 v1 = *(const float4*)(gbase + o1);
    float4 v2 = *(const float4*)(gbase + o2);
    float4 v3 = *(const float4*)(gbase + o3);
    acc.x += v0.x; acc.y += v0.y; acc.z += v0.z; acc.w += v0.w;
    acc.x += v1.x; acc.y += v1.y; acc.z += v1.z; acc.w += v1.w;
    acc.x += v2.x; acc.y += v2.y; acc.z += v2.z; acc.w += v2.w;
    acc.x += v3.x; acc.y += v3.y; acc.z += v3.z; acc.w += v3.w;
  }
  for (; s < M; s++) {
    float4 v0 = *(const float4*)(gbase + slist[s]);
    acc.x += v0.x; acc.y += v0.y; acc.z += v0.z; acc.w += v0.w;
  }

  // 3. LIF membrane update (registers)
  size_t sbase = (size_t)b * RR + j * 1024 + 4 * tid;
  int pbase = j * 1024 + 4 * tid;
  float4 drv4 = *(const float4*)(drv_t + sbase);
  float4 mem4 = *(const float4*)(memv + sbase);
  float4 sp4 = *(const float4*)(spike + sbase);
  float4 tt4 = *(const float4*)(ttr + sbase);
  float4 tr4 = *(const float4*)(rtr + sbase);
  float4 tc4 = *(const float4*)(ctr + sbase);
  float4 dec4 = *(const float4*)(P + 1 * RR + pbase);
  float4 tb4 = *(const float4*)(P + 2 * RR + pbase);
  float4 rb4 = *(const float4*)(P + 4 * RR + pbase);
  float4 cb4 = *(const float4*)(P + 6 * RR + pbase);
  float mn[4], th[4];
  {
    const float* dv = (const float*)&drv4;
    const float* mv = (const float*)&mem4;
    const float* sv = (const float*)&sp4;
    const float* t1 = (const float*)&tt4;
    const float* t2 = (const float*)&tr4;
    const float* t3 = (const float*)&tc4;
    const float* dc = (const float*)&dec4;
    const float* b1 = (const float*)&tb4;
    const float* b2 = (const float*)&rb4;
    const float* b3 = (const float*)&cb4;
    const float* ac = (const float*)&acc;
#pragma unroll
    for (int c = 0; c < 4; c++) {
      float rf = 0.5f + b2[c] * t2[c];
      float cu = b3[c] * t3[c];
      th[c] = 0.5f + b1[c] * t1[c];
      mn[c] = (mv[c] - sv[c] * rf) * dc[c] + (dv[c] + ac[c]) + cu;
    }
  }
  unsigned k4[4];
#pragma unroll
  for (int c = 0; c < 4; c++) k4[c] = fkey(mn[c]);

  // 4. radix select: u818 = 818th ascending (0-indexed) of the 1024 keys
#pragma unroll
  for (int pass = 0; pass < 4; pass++) {
    int shift = 24 - pass * 8;
    unsigned maskhi = (pass == 0) ? 0u : (0xFFFFFFFFu << (shift + 8));
    hist[tid] = 0u;
    __syncthreads();  // A
    unsigned pfx = s_prefix;
    unsigned rank = s_rank;
#pragma unroll
    for (int c = 0; c < 4; c++)
      if ((k4[c] & maskhi) == (pfx & maskhi)) atomicAdd(&hist[(k4[c] >> shift) & 255u], 1u);
    __syncthreads();  // B
    unsigned cnt0 = hist[tid];
    unsigned v = cnt0;
    for (int o = 1; o < 64; o <<= 1) {
      unsigned n = (unsigned)__shfl_up((int)v, o, 64);
      if (lane >= o) v += n;
    }
    if (lane == 63) wtot[wv] = v;
    __syncthreads();  // C
    unsigned add = 0;
    for (int w = 0; w < wv; w++) add += wtot[w];
    unsigned incl = v + add;
    unsigned excl = incl - cnt0;
    if (rank >= excl && rank < incl) {  // exactly one bin (cnt0>0 bins only)
      s_prefix = pfx | (((unsigned)tid) << shift);
      s_rank = rank - excl;
    }
    __syncthreads();  // D (also guards next pass's hist-zero vs cnt0 reads)
  }
  unsigned u818 = s_prefix;
  {
    int cl = 0;
    unsigned mnk = 0xFFFFFFFFu;
#pragma unroll
    for (int c = 0; c < 4; c++) {
      cl += (k4[c] <= u818) ? 1 : 0;
      if (k4[c] > u818) mnk = min(mnk, k4[c]);
    }
    atomicAdd(&s_cle, (unsigned)cl);
    atomicMin(&s_min, mnk);
  }
  __syncthreads();
  unsigned u819 = (s_cle >= 820u) ? u818 : s_min;
  float f818 = fkeyinv(u818), f819 = fkeyinv(u819);
  float nps = f818 + (0.8f * 1023.0f - 818.0f) * (f819 - f818);

  // 5. spike decision + state write + trace update
  float4 td4 = *(const float4*)(P + 3 * RR + pbase);
  float4 rd4 = *(const float4*)(P + 5 * RR + pbase);
  float4 cd4 = *(const float4*)(P + 7 * RR + pbase);
  float4 ss4 = *(const float4*)(ssum + sbase);
  float mw[4];
  int flg[4];
  {
    const float* d1 = (const float*)&td4;
    const float* d2 = (const float*)&rd4;
    const float* d3 = (const float*)&cd4;
    float* t1 = (float*)&tt4;
    float* t2 = (float*)&tr4;
    float* t3 = (float*)&tc4;
    float* sv = (float*)&sp4;
    float* mv = (float*)&mem4;
    float* ss = (float*)&ss4;
#pragma unroll
    for (int c = 0; c < 4; c++) {
      mw[c] = fmaxf(mn[c] - nps, 0.f);
      float sk = (mw[c] - th[c] > 0.f) ? 1.f : 0.f;
      flg[c] = (int)sk;
      mv[c] = mw[c];
      t1[c] = t1[c] * d1[c] + sk;
      t2[c] = t2[c] * d2[c] + sk;
      t3[c] = t3[c] * d3[c] + sk;
      sv[c] = sk;
      ss[c] += sk;
    }
  }
  *(float4*)(memv + sbase) = mem4;
  *(float4*)(spike + sbase) = sp4;
  *(float4*)(ttr + sbase) = tt4;
  *(float4*)(rtr + sbase) = tr4;
  *(float4*)(ctr + sbase) = tc4;
  *(float4*)(ssum + sbase) = ss4;

  // 6. compact spike list for this (b,j) group, ascending i, store r*RR
  int cnt = flg[0] + flg[1] + flg[2] + flg[3];
  int inc = cnt;
  for (int o = 1; o < 64; o <<= 1) {
    int n = __shfl_up(inc, o, 64);
    if (lane >= o) inc += n;
  }
  if (lane == 63) wtot[wv] = (unsigned)inc;
  __syncthreads();
  int base = inc - cnt;
  for (int w = 0; w < wv; w++) base += (int)wtot[w];
  int lb = (b * NB + j) * 256;
#pragma unroll
  for (int c = 0; c < 4; c++) {
    if (flg[c]) {
      int r = (4 * tid + c) * 5 + j;
      if (base < 256) idx_out[lb + base] = r * RR;
      base++;
    }
  }
  if (tid == 255) cnt_out[b * NB + j] = base > 256 ? 256 : base;
}

// ---------- readout: out[b,c] = dot(ssum_q[b,:], Wm_p[c,:])/24 + bm[c] ----------
__global__ __launch_bounds__(256) void k_readout(const float* __restrict__ ssum,
                                                 const float* __restrict__ Wmp,
                                                 const float* __restrict__ bm,
                                                 float* __restrict__ out) {
  __shared__ float red[4];
  int c = blockIdx.x;
  int b = blockIdx.y;
  int tid = threadIdx.x;
  const float4* sp = (const float4*)(ssum + (size_t)b * RR);
  const float4* wp = (const float4*)(Wmp + (size_t)c * RR);
  float acc = 0.f;
#pragma unroll
  for (int i = 0; i < 5; i++) {
    float4 s4 = sp[i * 256 + tid];
    float4 w4 = wp[i * 256 + tid];
    acc += s4.x * w4.x + s4.y * w4.y + s4.z * w4.z + s4.w * w4.w;
  }
  for (int o = 32; o > 0; o >>= 1) acc += __shfl_down(acc, o, 64);
  if ((tid & 63) == 0) red[tid >> 6] = acc;
  __syncthreads();
  if (tid == 0)
    out[b * CC + c] = (red[0] + red[1] + red[2] + red[3]) * (1.0f / 24.0f) + bm[c];
}

extern "C" void kernel_launch(void* const* d_in, const int* in_sizes, int n_in,
                              void* d_out, int out_size, void* d_ws, size_t ws_size,
                              hipStream_t stream) {
  const float* x = (const float*)d_in[0];
  const float* ln_g = (const float*)d_in[1];
  const float* ln_b = (const float*)d_in[2];
  const float* Wp = (const float*)d_in[3];
  const float* bp = (const float*)d_in[4];
  const float* Wl = (const float*)d_in[5];
  const float* bl = (const float*)d_in[6];
  const float* Wm = (const float*)d_in[7];
  const float* bm = (const float*)d_in[8];
  const float* decay = (const float*)d_in[9];
  const float* thr_beta = (const float*)d_in[10];
  const float* thr_decay = (const float*)d_in[11];
  const float* ref_beta = (const float*)d_in[12];
  const float* ref_decay = (const float*)d_in[13];
  const float* cur_beta = (const float*)d_in[14];
  const float* cur_decay = (const float*)d_in[15];
  const float* proj_mask = (const float*)d_in[16];
  const float* lat_mask = (const float*)d_in[17];
  float* out = (float*)d_out;

  float* ws = (float*)d_ws;
  float* WlTp = ws;                                  // R*R
  float* Wpm = WlTp + (size_t)RR * RR;               // R*D
  float* xn = Wpm + (size_t)RR * DD;                 // T*B*D
  float* drive = xn + (size_t)TSTEPS * BB * DD;      // T*B*R
  float* state = drive + (size_t)TSTEPS * BB * RR;   // 6 * B*R
  float* spike = state;
  float* memv = spike + (size_t)BB * RR;
  float* ttr = memv + (size_t)BB * RR;
  float* rtr = ttr + (size_t)BB * RR;
  float* ctr = rtr + (size_t)BB * RR;
  float* ssum = ctr + (size_t)BB * RR;
  float* P = ssum + (size_t)BB * RR;                 // 8 * R params
  float* Wmp = P + 8 * RR;                           // C*R
  int* idxg = (int*)(Wmp + (size_t)CC * RR);         // 2 * B*NB*256
  int* cntg = idxg + 2 * BB * NB * 256;              // 2 * B*NB

  hipLaunchKernelGGL(k_zero, dim3(512), dim3(256), 0, stream, state, cntg);
  hipLaunchKernelGGL(k_prep_params, dim3((RR + 255) / 256), dim3(256), 0, stream,
                     bp, bl, decay, thr_beta, thr_decay, ref_beta, ref_decay,
                     cur_beta, cur_decay, P);
  hipLaunchKernelGGL(k_prep_wm, dim3(CC), dim3(256), 0, stream, Wm, Wmp);
  hipLaunchKernelGGL(k_prep_wpm, dim3(RR), dim3(256), 0, stream, Wp, proj_mask, Wpm);
  hipLaunchKernelGGL(k_transpose_p, dim3(RR / 32, RR / 160), dim3(32, 8), 0, stream,
                     Wl, lat_mask, WlTp);
  hipLaunchKernelGGL(k_layernorm, dim3(TSTEPS * BB), dim3(256), 0, stream,
                     x, ln_g, ln_b, xn);
  hipLaunchKernelGGL(k_gemm_drive, dim3(RR / 64, TSTEPS * BB / 64), dim3(256), 0, stream,
                     xn, Wpm, P /* bp+bl at P[0] */, drive);
  for (int t = 0; t < TSTEPS; t++) {
    int pi = t & 1, po = (t + 1) & 1;
    hipLaunchKernelGGL(k_step, dim3(NB, BB), dim3(256), 0, stream,
                       drive + (size_t)t * BB * RR, WlTp, P,
                       spike, memv, ttr, rtr, ctr, ssum,
                       idxg + pi * BB * NB * 256, cntg + pi * BB * NB,
                       idxg + po * BB * NB * 256, cntg + po * BB * NB);
  }
  hipLaunchKernelGGL(k_readout, dim3(CC, BB), dim3(256), 0, stream, ssum, Wmp, bm, out);
}